// Round 2
// baseline (158.482 us; speedup 1.0000x reference)
//
#include <hip/hip_runtime.h>
#include <hip/hip_bf16.h>
#include <stdint.h>

#define N 8192
#define FIN 128
#define H 64
#define QB 16
#define MB 128
#define NIT (N / MB)

typedef __attribute__((ext_vector_type(8))) short short8;
typedef __attribute__((ext_vector_type(4))) float f32x4;

#define MFMA16(a, b, c) __builtin_amdgcn_mfma_f32_16x16x32_bf16(a, b, c, 0, 0, 0)

static __device__ __forceinline__ unsigned short f2bf(float f) {
    unsigned int u = __float_as_uint(f);
    unsigned int r = (u + 0x7FFFu + ((u >> 16) & 1u)) >> 16;
    return (unsigned short)r;
}

// -------- kernel 0: W[128,64] f32 -> W^T[64,128] bf16 (both weights) --------
__global__ __launch_bounds__(256) void wprep_kernel(const float* __restrict__ W1,
                                                    const float* __restrict__ W2,
                                                    unsigned short* __restrict__ W1T,
                                                    unsigned short* __restrict__ W2T) {
    const int i = blockIdx.x * 256 + threadIdx.x;  // 8192 total
    const int h = i >> 7, f = i & 127;
    W1T[i] = f2bf(W1[f * H + h]);
    W2T[i] = f2bf(W2[f * H + h]);
}

// -------- kernel 1: MFMA projection  seq[8192,128] @ W[128,64] -> Q(=V), K bf16 --------
// 4 waves/block, 16 rows/wave, 64 rows/block, 128 blocks. 32 MFMAs/wave.
__global__ __launch_bounds__(256) void proj_kernel(const float* __restrict__ seq,
                                                   const unsigned short* __restrict__ W1T,
                                                   const unsigned short* __restrict__ W2T,
                                                   unsigned short* __restrict__ Qb,
                                                   unsigned short* __restrict__ Kb) {
    const int tid = threadIdx.x;
    const int w = tid >> 6, lane = tid & 63;
    const int g = lane >> 4, c = lane & 15;
    const int r0 = blockIdx.x * 64 + w * 16;

    short8 af[4];  // A-frags: row=c, k=kc*32 + g*8 + j  (f32 loaded, cvt to bf16)
#pragma unroll
    for (int kc = 0; kc < 4; ++kc) {
        const float* sp = seq + (size_t)(r0 + c) * FIN + kc * 32 + g * 8;
        const f32x4 s0 = *(const f32x4*)sp;
        const f32x4 s1 = *(const f32x4*)(sp + 4);
        short8 v;
#pragma unroll
        for (int j = 0; j < 4; ++j) {
            v[j] = (short)f2bf(s0[j]);
            v[4 + j] = (short)f2bf(s1[j]);
        }
        af[kc] = v;
    }

    f32x4 qa[4] = {}, ka[4] = {};
#pragma unroll
    for (int kc = 0; kc < 4; ++kc) {
#pragma unroll
        for (int ht = 0; ht < 4; ++ht) {
            const short8 w1f = *(const short8*)(W1T + (size_t)(ht * 16 + c) * FIN + kc * 32 + g * 8);
            const short8 w2f = *(const short8*)(W2T + (size_t)(ht * 16 + c) * FIN + kc * 32 + g * 8);
            qa[ht] = MFMA16(af[kc], w1f, qa[ht]);
            ka[ht] = MFMA16(af[kc], w2f, ka[ht]);
        }
    }
#pragma unroll
    for (int ht = 0; ht < 4; ++ht)
#pragma unroll
        for (int r = 0; r < 4; ++r) {
            const int row = r0 + g * 4 + r;  // C layout: row = (lane>>4)*4 + reg
            Qb[(size_t)row * H + ht * 16 + c] = f2bf(qa[ht][r]);
            Kb[(size_t)row * H + ht * 16 + c] = f2bf(ka[ht][r]);
        }
}

// -------- kernel 2: transpose Qb[8192,64] -> QT[64,8192] (bf16, = V^T) --------
__global__ __launch_bounds__(256) void tr_kernel(const unsigned short* __restrict__ Qb,
                                                 unsigned short* __restrict__ QT) {
    __shared__ unsigned short t[64][65];
    const int m0 = blockIdx.x * 64;
    const int tid = threadIdx.x;
    for (int i = tid; i < 64 * 64; i += 256) {
        const int m = i >> 6, h = i & 63;
        t[h][m] = Qb[(size_t)(m0 + m) * H + h];
    }
    __syncthreads();
    for (int i = tid; i < 64 * 64; i += 256) {
        const int h = i >> 6, m = i & 63;
        QT[(size_t)h * N + m0 + m] = t[h][m];
    }
}

// -------- kernel 3: flash attention, no block barriers in main loop --------
// K/V^T are L2-resident (1 MB each): MFMA B-frags loaded straight from global.
// 4 waves/block, each wave owns a 32-key slice of the 128-key tile.
__global__ __launch_bounds__(256, 4) void flash_kernel(const unsigned short* __restrict__ Qb,
                                                       const unsigned short* __restrict__ Kb,
                                                       const unsigned short* __restrict__ QT,
                                                       const float* __restrict__ bias,
                                                       float* __restrict__ out) {
    __shared__ unsigned short Pt[4][16 * 40];  // per-wave P [q][m], stride 40 (80B) conflict-free
    __shared__ float redv[4][16][65];
    __shared__ float redd[4][16];

    const int tid = threadIdx.x;
    const int w = tid >> 6, lane = tid & 63;
    const int g = lane >> 4, c = lane & 15;
    const int q0 = blockIdx.x * QB;
    const int mwoff = w * 32;

    // Q A-fragments (row=c, k=g*8+j), H=64 -> 2 frags
    short8 qf0, qf1;
    {
        const unsigned short* qrow = Qb + (size_t)(q0 + c) * H + g * 8;
        qf0 = *(const short8*)(qrow);
        qf1 = *(const short8*)(qrow + 32);
    }

    f32x4 vals[4] = {};  // PV accum; D row=q(g*4+r), col=h(ht*16+c)
    float dsum[4] = {0.f, 0.f, 0.f, 0.f};

    const float* bbase = bias + (size_t)(q0 + g * 4) * N + c;  // + r*N + t*16 + m-offset
    float bcur[8];
#pragma unroll
    for (int t = 0; t < 2; ++t)
#pragma unroll
        for (int r = 0; r < 4; ++r)
            bcur[t * 4 + r] = bbase[(size_t)r * N + mwoff + t * 16];

    for (int it = 0; it < NIT; ++it) {
        const int m0 = it * MB;

        // current K fragments: per t the wave reads one contiguous 2KB block (L2 hit)
        short8 kf[2][2];
#pragma unroll
        for (int t = 0; t < 2; ++t) {
            const unsigned short* kr = Kb + (size_t)(m0 + mwoff + t * 16 + c) * H + g * 8;
            kf[t][0] = *(const short8*)(kr);
            kf[t][1] = *(const short8*)(kr + 32);
        }
        // current V^T fragments (B[k=m_local][col=h]): 64B segments, L2 hit
        short8 vf[4];
#pragma unroll
        for (int ht = 0; ht < 4; ++ht)
            vf[ht] = *(const short8*)(QT + (size_t)(ht * 16 + c) * N + m0 + mwoff + g * 8);

        // prefetch next iteration's bias (the real HBM stream)
        float bnext[8];
        if (it + 1 < NIT) {
            const int mn = m0 + MB + mwoff;
#pragma unroll
            for (int t = 0; t < 2; ++t)
#pragma unroll
                for (int r = 0; r < 4; ++r)
                    bnext[t * 4 + r] = bbase[(size_t)r * N + mn + t * 16];
        }

        // ---- QK^T (16x32 slice), exp, weight by bias ----
        unsigned short pw[8];
#pragma unroll
        for (int t = 0; t < 2; ++t) {
            f32x4 acc = {};
            acc = MFMA16(qf0, kf[t][0], acc);
            acc = MFMA16(qf1, kf[t][1], acc);
#pragma unroll
            for (int r = 0; r < 4; ++r) {
                const float p = __expf(acc[r] * 0.125f) * bcur[t * 4 + r];
                dsum[r] += p;
                pw[t * 4 + r] = f2bf(p);
            }
        }

        // ---- P -> wave-local LDS (conflict-free), read back as A-frag ----
        unsigned short* pp = (unsigned short*)Pt[w];
#pragma unroll
        for (int t = 0; t < 2; ++t)
#pragma unroll
            for (int r = 0; r < 4; ++r)
                pp[(g * 4 + r) * 40 + t * 16 + c] = pw[t * 4 + r];
        __builtin_amdgcn_wave_barrier();
        const short8 pa = *(const short8*)(pp + c * 40 + g * 8);

        // ---- PV: vals[ht] += P(16x32) @ V(32x16) ----
#pragma unroll
        for (int ht = 0; ht < 4; ++ht)
            vals[ht] = MFMA16(pa, vf[ht], vals[ht]);

        if (it + 1 < NIT) {
#pragma unroll
            for (int i = 0; i < 8; ++i) bcur[i] = bnext[i];
        }
    }

    // ---- reduce denominator across the 16 c-lanes ----
#pragma unroll
    for (int r = 0; r < 4; ++r) {
        float v = dsum[r];
        v += __shfl_xor(v, 1);
        v += __shfl_xor(v, 2);
        v += __shfl_xor(v, 4);
        v += __shfl_xor(v, 8);
        dsum[r] = v;
    }
    // ---- cross-wave reduction in LDS ----
#pragma unroll
    for (int ht = 0; ht < 4; ++ht)
#pragma unroll
        for (int r = 0; r < 4; ++r)
            redv[w][g * 4 + r][ht * 16 + c] = vals[ht][r];
    if (c == 0) {
#pragma unroll
        for (int r = 0; r < 4; ++r) redd[w][g * 4 + r] = dsum[r];
    }
    __syncthreads();

    const int h = tid & 63;
    for (int qq = tid >> 6; qq < QB; qq += 4) {
        const float v = redv[0][qq][h] + redv[1][qq][h] + redv[2][qq][h] + redv[3][qq][h];
        const float d = redd[0][qq] + redd[1][qq] + redd[2][qq] + redd[3][qq];
        const float x = v / (d + 1e-19f);
        out[(size_t)(q0 + qq) * H + h] = x > 0.f ? x : expm1f(x);
    }
}

extern "C" void kernel_launch(void* const* d_in, const int* in_sizes, int n_in,
                              void* d_out, int out_size, void* d_ws, size_t ws_size,
                              hipStream_t stream) {
    const float* seq  = (const float*)d_in[0];
    const float* bias = (const float*)d_in[1];
    const float* W1   = (const float*)d_in[2];
    const float* W2   = (const float*)d_in[3];
    // d_in[4] = bias_zero (all zeros) -- folded out
    float* out = (float*)d_out;

    unsigned short* Qb  = (unsigned short*)d_ws;   // N*H bf16 = 1 MB (also V)
    unsigned short* Kb  = Qb + (size_t)N * H;      // 1 MB
    unsigned short* QT  = Kb + (size_t)N * H;      // 1 MB (V^T)
    unsigned short* W1T = QT + (size_t)N * H;      // 16 KB
    unsigned short* W2T = W1T + (size_t)H * FIN;   // 16 KB

    wprep_kernel<<<32, 256, 0, stream>>>(W1, W2, W1T, W2T);
    proj_kernel<<<N / 64, 256, 0, stream>>>(seq, W1T, W2T, Qb, Kb);
    tr_kernel<<<N / 64, 256, 0, stream>>>(Qb, QT);
    flash_kernel<<<N / QB, 256, 0, stream>>>(Qb, Kb, QT, bias, out);
}